// Round 2
// baseline (295.763 us; speedup 1.0000x reference)
//
#include <hip/hip_runtime.h>

#define N_CLASSES 91
#define NBINS (3 * N_CLASSES)   // 273
#define HCOLS 32
#define HSIZE (NBINS * HCOLS)   // 8736 words = 34944 B

// Zero the 273 bins + 1 ticket counter (ws is re-poisoned to 0xAA each launch).
__global__ void miou_zero_ws(unsigned int* __restrict__ ws) {
    int i = threadIdx.x;
    if (i < NBINS + 1) ws[i] = 0u;
}

__global__ __launch_bounds__(256) void miou_hist(const float* __restrict__ inp,
                                                 const int* __restrict__ tgt,
                                                 unsigned int* __restrict__ ws,
                                                 const int* __restrict__ smooth,
                                                 float* __restrict__ out,
                                                 int n4) {
    // 32-column replicated histograms: word index = bin*32 + (lane&31)
    // -> bank = lane&31 always (2 lanes/bank = free), same-address collisions
    //    only when lanes i and i+32 hold the same class (p ~ 1/91).
    __shared__ unsigned int h[HSIZE];
    const int tid = threadIdx.x;
    const int col = tid & 31;

    for (int i = tid; i < HSIZE; i += 256) h[i] = 0u;
    __syncthreads();

    const int stride = gridDim.x * blockDim.x;
    for (int idx = blockIdx.x * blockDim.x + tid; idx < n4; idx += stride) {
        const float4 f = reinterpret_cast<const float4*>(inp)[idx];
        const int4  t = reinterpret_cast<const int4*>(tgt)[idx];
        const int x0 = (int)f.x, x1 = (int)f.y, x2 = (int)f.z, x3 = (int)f.w;

        atomicAdd(&h[x0 * HCOLS + col], 1u);
        atomicAdd(&h[x1 * HCOLS + col], 1u);
        atomicAdd(&h[x2 * HCOLS + col], 1u);
        atomicAdd(&h[x3 * HCOLS + col], 1u);

        atomicAdd(&h[(N_CLASSES + t.x) * HCOLS + col], 1u);
        atomicAdd(&h[(N_CLASSES + t.y) * HCOLS + col], 1u);
        atomicAdd(&h[(N_CLASSES + t.z) * HCOLS + col], 1u);
        atomicAdd(&h[(N_CLASSES + t.w) * HCOLS + col], 1u);

        if (x0 == t.x) atomicAdd(&h[(2 * N_CLASSES + x0) * HCOLS + col], 1u);
        if (x1 == t.y) atomicAdd(&h[(2 * N_CLASSES + x1) * HCOLS + col], 1u);
        if (x2 == t.z) atomicAdd(&h[(2 * N_CLASSES + x2) * HCOLS + col], 1u);
        if (x3 == t.w) atomicAdd(&h[(2 * N_CLASSES + x3) * HCOLS + col], 1u);
    }
    __syncthreads();

    // Flush: sum the 32 columns per bin (rotated start keeps banks spread),
    // one global atomic per (block, bin).
    for (int i = tid; i < NBINS; i += 256) {
        unsigned int s = 0;
        const int base = i * HCOLS;
        #pragma unroll
        for (int k = 0; k < HCOLS; ++k) s += h[base + ((k + tid) & 31)];
        if (s) atomicAdd(&ws[i], s);
    }
    __threadfence();

    // Last-block-done ticket -> fused finalize.
    __shared__ unsigned int lastflag;
    if (tid == 0) {
        const unsigned int old = atomicAdd(&ws[NBINS], 1u);
        lastflag = (old == (unsigned int)gridDim.x - 1u) ? 1u : 0u;
    }
    __syncthreads();
    if (lastflag) {
        float s = 0.f, cnt = 0.f;
        if (tid < N_CLASSES) {
            // atomicAdd(p,0) = device-coherent read (bypasses any stale L1)
            const float a     = (float)atomicAdd(&ws[tid], 0u);
            const float b     = (float)atomicAdd(&ws[N_CLASSES + tid], 0u);
            const float inter = (float)atomicAdd(&ws[2 * N_CLASSES + tid], 0u);
            const float uni   = a + b - inter;
            if (uni != 0.f) {
                const float sm = (float)(*smooth);
                s   = (inter + sm) / (uni + sm);
                cnt = 1.f;
            }
        }
        #pragma unroll
        for (int off = 32; off > 0; off >>= 1) {
            s   += __shfl_down(s, off, 64);
            cnt += __shfl_down(cnt, off, 64);
        }
        __shared__ float rs[4], rc[4];
        const int w = tid >> 6;
        if ((tid & 63) == 0) { rs[w] = s; rc[w] = cnt; }
        __syncthreads();
        if (tid == 0) out[0] = (rs[0] + rs[1] + rs[2] + rs[3]) /
                               (rc[0] + rc[1] + rc[2] + rc[3]);
    }
}

extern "C" void kernel_launch(void* const* d_in, const int* in_sizes, int n_in,
                              void* d_out, int out_size, void* d_ws, size_t ws_size,
                              hipStream_t stream) {
    const float* inp    = (const float*)d_in[0];
    const int*   tgt    = (const int*)d_in[1];
    const int*   smooth = (const int*)d_in[2];
    float* out = (float*)d_out;
    unsigned int* ws = (unsigned int*)d_ws;

    const int n  = in_sizes[0];   // 16,777,216
    const int n4 = n >> 2;        // 4,194,304

    miou_zero_ws<<<1, 512, 0, stream>>>(ws);

    const int block = 256;
    int grid = (n4 + block - 1) / block;
    if (grid > 2048) grid = 2048;  // grid-stride: 8 vec4 iters/thread
    miou_hist<<<grid, block, 0, stream>>>(inp, tgt, ws, smooth, out, n4);
}